// Round 6
// baseline (675.941 us; speedup 1.0000x reference)
//
#include <hip/hip_runtime.h>

#define DIMS 128
#define RPB 64           // rows per bucket
#define CAP 3072         // edge capacity per bucket (avg 2047, ~23 sigma margin)
#define NBK_MAX 1600
#define NBINS 1024       // 64 rows x 16 column bands (col band = col>>13 in [0,12])
#define NBANDS 13        // bands actually populated (col < 100000 < 13*8192)
#define RPW 16           // rows per wave in spmm (divides RPB)

typedef _Float16 half_t;
typedef _Float16 half2_t __attribute__((ext_vector_type(2)));
typedef unsigned short ushort_t;

static __device__ __forceinline__ unsigned halfbits(float v) {
    half_t h = (half_t)v;
    unsigned short us;
    __builtin_memcpy(&us, &h, 2);
    return (unsigned)us;
}
static __device__ __forceinline__ half2_t h2(int b) { return __builtin_bit_cast(half2_t, b); }
static __device__ __forceinline__ int ih(half2_t h) { return __builtin_bit_cast(int, h); }

// fp32 -> fp16 convert (x -> xh), 2 elems/thread
__global__ void cvt_kernel(const float* __restrict__ src, half_t* __restrict__ dst, int n2) {
    int i = blockIdx.x * blockDim.x + threadIdx.x;
    if (i >= n2) return;
    float2 v = reinterpret_cast<const float2*>(src)[i];
    half2_t h;
    h.x = (half_t)v.x;
    h.y = (half_t)v.y;
    reinterpret_cast<half2_t*>(&dst[0])[i] = h;
}

// Binning pass: append (rl<<26 | col<<8, half2{v,v}) to bucket row>>6.
// col<<8 IS the byte offset into the fp16 table (col*128*2).
__global__ __launch_bounds__(512) void binA_kernel(
    const int* __restrict__ row, const int* __restrict__ col,
    const float* __restrict__ val, int E, int nbk,
    int* __restrict__ fill, int2* __restrict__ staged) {
    __shared__ int cnt[NBK_MAX];
    __shared__ int base[NBK_MAX];
    const int t = threadIdx.x;
    const int tile0 = blockIdx.x * 8192;
    for (int j = t; j < nbk; j += 512) cnt[j] = 0;
    __syncthreads();
    for (int k = 0; k < 4; ++k) {
        int e = tile0 + (k * 512 + t) * 4;
        if (e + 3 < E) {
            int4 r4 = *reinterpret_cast<const int4*>(&row[e]);
            atomicAdd(&cnt[r4.x >> 6], 1);
            atomicAdd(&cnt[r4.y >> 6], 1);
            atomicAdd(&cnt[r4.z >> 6], 1);
            atomicAdd(&cnt[r4.w >> 6], 1);
        } else {
            for (int j = e; j < E; ++j) atomicAdd(&cnt[row[j] >> 6], 1);
        }
    }
    __syncthreads();
    for (int j = t; j < nbk; j += 512) {
        int c = cnt[j];
        base[j] = c ? atomicAdd(&fill[j], c) : 0;
        cnt[j] = 0;
    }
    __syncthreads();
    for (int k = 0; k < 4; ++k) {
        int e = tile0 + (k * 512 + t) * 4;
        int n = (e + 3 < E) ? 4 : max(0, E - e);
        if (n == 4) {
            int4 r4 = *reinterpret_cast<const int4*>(&row[e]);
            int4 c4 = *reinterpret_cast<const int4*>(&col[e]);
            float4 v4 = *reinterpret_cast<const float4*>(&val[e]);
            int rr[4] = {r4.x, r4.y, r4.z, r4.w};
            int cc[4] = {c4.x, c4.y, c4.z, c4.w};
            float vv[4] = {v4.x, v4.y, v4.z, v4.w};
#pragma unroll
            for (int j = 0; j < 4; ++j) {
                int b = rr[j] >> 6;
                int p = base[b] + atomicAdd(&cnt[b], 1);
                if (p < CAP) {
                    unsigned hb = halfbits(vv[j]);
                    int2 pk;
                    pk.x = (int)(((unsigned)(rr[j] & 63) << 26) | ((unsigned)cc[j] << 8));
                    pk.y = (int)((hb << 16) | hb);
                    staged[(size_t)b * CAP + p] = pk;
                }
            }
        } else {
            for (int j = e; j < e + n; ++j) {
                int r = row[j];
                int b = r >> 6;
                int p = base[b] + atomicAdd(&cnt[b], 1);
                if (p < CAP) {
                    unsigned hb = halfbits(val[j]);
                    int2 pk;
                    pk.x = (int)(((unsigned)(r & 63) << 26) | ((unsigned)col[j] << 8));
                    pk.y = (int)((hb << 16) | hb);
                    staged[(size_t)b * CAP + p] = pk;
                }
            }
        }
    }
}

// In-LDS counting sort of one bucket by (row_local, col band): key =
// (rl<<4)|band. Emits the per-bin START table (binoff, ushort per bin):
// binoff[bucket*1024 + rl*16 + band] = start of that (row,band) range
// relative to the bucket base. Range end = next bin's start (bins 13..15
// are empty so band 12's end == bin 13's start; always in-bounds).
__global__ __launch_bounds__(512) void sort_bucket(
    const int* __restrict__ fill, int2* __restrict__ staged,
    ushort_t* __restrict__ binoff) {
    __shared__ int2 outb[CAP];   // 24 KB
    __shared__ int cur[NBINS];   // 4 KB
    __shared__ int wsum[8];
    const int b = blockIdx.x;
    const int t = threadIdx.x;
    const int w = t >> 6, lane = t & 63;
    const int cnt = min(fill[b], CAP);
    int2* gb = staged + (size_t)b * CAP;

    cur[2 * t] = 0;
    cur[2 * t + 1] = 0;
    __syncthreads();
    for (int i = t; i < cnt; i += 512) {
        unsigned k = (unsigned)gb[i].x;
        int key = (int)((k >> 26) << 4) | (int)((k >> 21) & 0xF);
        atomicAdd(&cur[key], 1);
    }
    __syncthreads();
    int h0 = cur[2 * t], h1 = cur[2 * t + 1];
    int s = h0 + h1;
    int v = s;
    for (int d = 1; d < 64; d <<= 1) {
        int u = __shfl_up(v, d, 64);
        if (lane >= d) v += u;
    }
    if (lane == 63) wsum[w] = v;
    __syncthreads();
    if (t < 8) {
        int ws = wsum[t];
        int vv = ws;
        for (int d = 1; d < 8; d <<= 1) {
            int u = __shfl_up(vv, d, 64);
            if (t >= d) vv += u;
        }
        wsum[t] = vv - ws;
    }
    __syncthreads();
    int excl = wsum[w] + (v - s);
    cur[2 * t] = excl;
    cur[2 * t + 1] = excl + h0;
    // write bin starts (values just computed, no barrier needed)
    {
        ushort2 u2;
        u2.x = (ushort_t)excl;
        u2.y = (ushort_t)(excl + h0);
        reinterpret_cast<ushort2*>(binoff + (size_t)b * NBINS)[t] = u2;
    }
    __syncthreads();
    for (int i = t; i < cnt; i += 512) {
        int2 pk = gb[i];
        unsigned k = (unsigned)pk.x;
        int key = (int)((k >> 26) << 4) | (int)((k >> 21) & 0xF);
        int p = atomicAdd(&cur[key], 1);
        outb[p] = pk;
    }
    __syncthreads();
    for (int i = t; i < cnt; i += 512) gb[i] = outb[i];
}

// ---------------- SpMM: band-phased, 4 parallel row-chains per group --------
// Each wave owns RPW=16 rows; group g owns rows r0+4g..r0+4g+3 with their full
// 128-dim accumulators in registers. Band loop OUTER (confirmed round 5:
// FETCH 370->221 MB). Inner loop restructured for MLP: per step s, issue the
// 4 rows' edge-record loads (group-uniform -> broadcast), then the 4
// independent dwordx4 gathers, then 16 pk_fma -- 4 gather chains in flight
// per group instead of 1. Rows shorter than the group's max segment are
// masked: clamped (L1-hot) gather address, val=0. All acc/array indices are
// compile-time (full unroll over rr, constant trip 4 -- rule #20).
// MODE 0: emb_out = A*xh;   acc_h = xh + A*xh        (layer 1)
// MODE 1: emb_out = A*e1;   acc_h += A*e1            (layer 2, emb_out==xh reused)
// MODE 2: out = (acc_h + A*e2) * 0.25  (fp32 final)  (layer 3)
template <int MODE>
__global__ __launch_bounds__(256, 7) void spmm_kernel(
    const half_t* __restrict__ emb_in, const ushort_t* __restrict__ binoff,
    const int2* __restrict__ staged, int N,
    half_t* __restrict__ emb_out, half_t* __restrict__ acc_h,
    float* __restrict__ out) {
    const int wid = (blockIdx.x * blockDim.x + threadIdx.x) >> 6;
    const int lane = threadIdx.x & 63;
    const int r0 = wid * RPW;
    if (r0 >= N) return;
    const int bucket = r0 >> 6;
    const int g = lane >> 4;                          // group 0..3 -> rows r0+4g..r0+4g+3
    const int l16 = lane & 15;
    const unsigned q16 = (unsigned)l16 << 4;          // byte offset of this lane's 8 dims
    const int2* eb = staged + (size_t)bucket * CAP;
    const char* tbl = reinterpret_cast<const char*>(emb_in);
    const ushort_t* bo = binoff + (size_t)bucket * NBINS + (((r0 & 63) + (g << 2)) << 4);

    half2_t acc[4][4];
#pragma unroll
    for (int u = 0; u < 4; ++u)
#pragma unroll
        for (int s = 0; s < 4; ++s) acc[u][s] = (half2_t)0;

    int bs[4], be[4];
#pragma unroll
    for (int rr = 0; rr < 4; ++rr) bs[rr] = (int)bo[rr * 16];

    for (int b = 1; b <= NBANDS; ++b) {
#pragma unroll
        for (int rr = 0; rr < 4; ++rr) be[rr] = (int)bo[rr * 16 + b];
        const int mx = max(max(be[0] - bs[0], be[1] - bs[1]),
                           max(be[2] - bs[2], be[3] - bs[3]));
        for (int s = 0; s < mx; ++s) {
            int2 e[4];
#pragma unroll
            for (int rr = 0; rr < 4; ++rr) {
                int j = bs[rr] + min(s, be[rr] - bs[rr] - 1);
                e[rr] = eb[max(j, 0)];
            }
            int4 t4[4];
#pragma unroll
            for (int rr = 0; rr < 4; ++rr) {
                t4[rr] = *reinterpret_cast<const int4*>(
                    tbl + (((unsigned)e[rr].x & 0x03FFFF00u) + q16));
            }
#pragma unroll
            for (int rr = 0; rr < 4; ++rr) {
                const half2_t vv = h2((s < be[rr] - bs[rr]) ? e[rr].y : 0);
                acc[rr][0] = h2(t4[rr].x) * vv + acc[rr][0];
                acc[rr][1] = h2(t4[rr].y) * vv + acc[rr][1];
                acc[rr][2] = h2(t4[rr].z) * vv + acc[rr][2];
                acc[rr][3] = h2(t4[rr].w) * vv + acc[rr][3];
            }
        }
#pragma unroll
        for (int rr = 0; rr < 4; ++rr) bs[rr] = be[rr];
    }

    // each group writes its own 4 rows; no cross-group reduction needed
#pragma unroll
    for (int rr = 0; rr < 4; ++rr) {
        const int r = r0 + (g << 2) + rr;
        const size_t o = (size_t)r * DIMS + ((size_t)l16 << 3);  // 8 halves / lane
        const half2_t a0 = acc[rr][0], a1 = acc[rr][1];
        const half2_t a2 = acc[rr][2], a3 = acc[rr][3];
        if (MODE == 0 || MODE == 1) {
            *reinterpret_cast<int4*>(&emb_out[o]) = make_int4(ih(a0), ih(a1), ih(a2), ih(a3));
        }
        if (MODE == 0) {
            int4 xv = *reinterpret_cast<const int4*>(&emb_in[o]);
            *reinterpret_cast<int4*>(&acc_h[o]) = make_int4(
                ih(h2(xv.x) + a0), ih(h2(xv.y) + a1), ih(h2(xv.z) + a2), ih(h2(xv.w) + a3));
        } else if (MODE == 1) {
            int4 cv = *reinterpret_cast<const int4*>(&acc_h[o]);
            *reinterpret_cast<int4*>(&acc_h[o]) = make_int4(
                ih(h2(cv.x) + a0), ih(h2(cv.y) + a1), ih(h2(cv.z) + a2), ih(h2(cv.w) + a3));
        } else {
            int4 cv = *reinterpret_cast<const int4*>(&acc_h[o]);
            half2_t c0 = h2(cv.x), c1 = h2(cv.y), c2 = h2(cv.z), c3 = h2(cv.w);
            float4 f0 = make_float4(((float)c0.x + (float)a0.x) * 0.25f,
                                    ((float)c0.y + (float)a0.y) * 0.25f,
                                    ((float)c1.x + (float)a1.x) * 0.25f,
                                    ((float)c1.y + (float)a1.y) * 0.25f);
            float4 f1 = make_float4(((float)c2.x + (float)a2.x) * 0.25f,
                                    ((float)c2.y + (float)a2.y) * 0.25f,
                                    ((float)c3.x + (float)a3.x) * 0.25f,
                                    ((float)c3.y + (float)a3.y) * 0.25f);
            float4* po = reinterpret_cast<float4*>(&out[o]);
            po[0] = f0;
            po[1] = f1;
        }
    }
}

// ---------------- launch ----------------

extern "C" void kernel_launch(void* const* d_in, const int* in_sizes, int n_in,
                              void* d_out, int out_size, void* d_ws, size_t ws_size,
                              hipStream_t stream) {
    const float* x = (const float*)d_in[0];
    const int* erow = (const int*)d_in[1];
    const int* ecol = (const int*)d_in[2];
    const float* eval = (const float*)d_in[3];
    const int N = in_sizes[0] / DIMS;  // 100000
    const int E = in_sizes[1];         // 3200000
    float* out = (float*)d_out;
    const int nbk = (N + RPB - 1) / RPB;  // 1563

    char* ws = (char*)d_ws;
    size_t off = 0;
    auto carve = [&](size_t bytes) {
        void* p = ws + off;
        off = (off + bytes + 255) & ~(size_t)255;
        return p;
    };
    half_t* xh = (half_t*)carve((size_t)N * DIMS * sizeof(half_t));  // also layer-2 output
    half_t* embB1 = (half_t*)carve((size_t)N * DIMS * sizeof(half_t));
    half_t* acc_h = (half_t*)carve((size_t)N * DIMS * sizeof(half_t));
    int2* staged = (int2*)carve((size_t)nbk * CAP * sizeof(int2));
    int* fill = (int*)carve((size_t)nbk * sizeof(int));
    ushort_t* binoff = (ushort_t*)carve((size_t)nbk * NBINS * sizeof(ushort_t));
    (void)ws_size;

    hipMemsetAsync(fill, 0, (size_t)nbk * sizeof(int), stream);
    const int n2 = N * DIMS / 2;
    cvt_kernel<<<(n2 + 255) / 256, 256, 0, stream>>>(x, xh, n2);
    binA_kernel<<<(E + 8191) / 8192, 512, 0, stream>>>(erow, ecol, eval, E, nbk, fill, staged);
    sort_bucket<<<nbk, 512, 0, stream>>>(fill, staged, binoff);

    const int waves = (N + RPW - 1) / RPW;        // 6250
    const int spmm_blocks = (waves + 3) / 4;      // 1563 blocks, fully co-resident
    spmm_kernel<0><<<spmm_blocks, 256, 0, stream>>>(xh, binoff, staged, N, embB1, acc_h, out);
    spmm_kernel<1><<<spmm_blocks, 256, 0, stream>>>(embB1, binoff, staged, N, xh, acc_h, out);
    spmm_kernel<2><<<spmm_blocks, 256, 0, stream>>>(xh, binoff, staged, N, embB1, acc_h, out);
}

// Round 7
// 588.720 us; speedup vs baseline: 1.1482x; 1.1482x over previous
//
#include <hip/hip_runtime.h>

#define DIMS 128
#define RPB 64           // rows per bucket
#define CAP 3072         // edge capacity per bucket (avg 2047, ~23 sigma margin)
#define NBK_MAX 1600
#define NBINS 1024       // per bucket: 16 bands x 64 rows (band-major: bin = band*64 + rl)
#define NBANDS 13        // bands actually populated (col < 100000 < 13*8192)
#define RPW 16           // rows per wave in spmm (divides RPB)

typedef _Float16 half_t;
typedef _Float16 half2_t __attribute__((ext_vector_type(2)));
typedef unsigned short ushort_t;

static __device__ __forceinline__ unsigned halfbits(float v) {
    half_t h = (half_t)v;
    unsigned short us;
    __builtin_memcpy(&us, &h, 2);
    return (unsigned)us;
}
static __device__ __forceinline__ half2_t h2(int b) { return __builtin_bit_cast(half2_t, b); }
static __device__ __forceinline__ int ih(half2_t h) { return __builtin_bit_cast(int, h); }

// fp32 -> fp16 convert (x -> xh), 2 elems/thread
__global__ void cvt_kernel(const float* __restrict__ src, half_t* __restrict__ dst, int n2) {
    int i = blockIdx.x * blockDim.x + threadIdx.x;
    if (i >= n2) return;
    float2 v = reinterpret_cast<const float2*>(src)[i];
    half2_t h;
    h.x = (half_t)v.x;
    h.y = (half_t)v.y;
    reinterpret_cast<half2_t*>(&dst[0])[i] = h;
}

// Binning pass: append (rl<<26 | col<<8, half2{v,v}) to bucket row>>6.
// col<<8 IS the byte offset into the fp16 table (col*128*2).
__global__ __launch_bounds__(512) void binA_kernel(
    const int* __restrict__ row, const int* __restrict__ col,
    const float* __restrict__ val, int E, int nbk,
    int* __restrict__ fill, int2* __restrict__ staged) {
    __shared__ int cnt[NBK_MAX];
    __shared__ int base[NBK_MAX];
    const int t = threadIdx.x;
    const int tile0 = blockIdx.x * 8192;
    for (int j = t; j < nbk; j += 512) cnt[j] = 0;
    __syncthreads();
    for (int k = 0; k < 4; ++k) {
        int e = tile0 + (k * 512 + t) * 4;
        if (e + 3 < E) {
            int4 r4 = *reinterpret_cast<const int4*>(&row[e]);
            atomicAdd(&cnt[r4.x >> 6], 1);
            atomicAdd(&cnt[r4.y >> 6], 1);
            atomicAdd(&cnt[r4.z >> 6], 1);
            atomicAdd(&cnt[r4.w >> 6], 1);
        } else {
            for (int j = e; j < E; ++j) atomicAdd(&cnt[row[j] >> 6], 1);
        }
    }
    __syncthreads();
    for (int j = t; j < nbk; j += 512) {
        int c = cnt[j];
        base[j] = c ? atomicAdd(&fill[j], c) : 0;
        cnt[j] = 0;
    }
    __syncthreads();
    for (int k = 0; k < 4; ++k) {
        int e = tile0 + (k * 512 + t) * 4;
        int n = (e + 3 < E) ? 4 : max(0, E - e);
        if (n == 4) {
            int4 r4 = *reinterpret_cast<const int4*>(&row[e]);
            int4 c4 = *reinterpret_cast<const int4*>(&col[e]);
            float4 v4 = *reinterpret_cast<const float4*>(&val[e]);
            int rr[4] = {r4.x, r4.y, r4.z, r4.w};
            int cc[4] = {c4.x, c4.y, c4.z, c4.w};
            float vv[4] = {v4.x, v4.y, v4.z, v4.w};
#pragma unroll
            for (int j = 0; j < 4; ++j) {
                int b = rr[j] >> 6;
                int p = base[b] + atomicAdd(&cnt[b], 1);
                if (p < CAP) {
                    unsigned hb = halfbits(vv[j]);
                    int2 pk;
                    pk.x = (int)(((unsigned)(rr[j] & 63) << 26) | ((unsigned)cc[j] << 8));
                    pk.y = (int)((hb << 16) | hb);
                    staged[(size_t)b * CAP + p] = pk;
                }
            }
        } else {
            for (int j = e; j < e + n; ++j) {
                int r = row[j];
                int b = r >> 6;
                int p = base[b] + atomicAdd(&cnt[b], 1);
                if (p < CAP) {
                    unsigned hb = halfbits(val[j]);
                    int2 pk;
                    pk.x = (int)(((unsigned)(r & 63) << 26) | ((unsigned)col[j] << 8));
                    pk.y = (int)((hb << 16) | hb);
                    staged[(size_t)b * CAP + p] = pk;
                }
            }
        }
    }
}

// In-LDS counting sort of one bucket, BAND-MAJOR key: bin = band*64 + rl.
// Within band b, all 64 rows' edges are contiguous and row-sorted, so a
// 4-row group's band-b range is ONE contiguous run. Emits per-bin starts
// (binoff ushort): range for (band b, rows R..R+3) = [bo[b*64+R], bo[b*64+R+4])
// (index b*64+64 == (b+1)*64, the next band's start -- always valid).
__global__ __launch_bounds__(512) void sort_bucket(
    const int* __restrict__ fill, int2* __restrict__ staged,
    ushort_t* __restrict__ binoff) {
    __shared__ int2 outb[CAP];   // 24 KB
    __shared__ int cur[NBINS];   // 4 KB
    __shared__ int wsum[8];
    const int b = blockIdx.x;
    const int t = threadIdx.x;
    const int w = t >> 6, lane = t & 63;
    const int cnt = min(fill[b], CAP);
    int2* gb = staged + (size_t)b * CAP;

    cur[2 * t] = 0;
    cur[2 * t + 1] = 0;
    __syncthreads();
    for (int i = t; i < cnt; i += 512) {
        unsigned k = (unsigned)gb[i].x;
        int key = (int)(((k >> 21) & 0xF) << 6) | (int)(k >> 26);
        atomicAdd(&cur[key], 1);
    }
    __syncthreads();
    int h0 = cur[2 * t], h1 = cur[2 * t + 1];
    int s = h0 + h1;
    int v = s;
    for (int d = 1; d < 64; d <<= 1) {
        int u = __shfl_up(v, d, 64);
        if (lane >= d) v += u;
    }
    if (lane == 63) wsum[w] = v;
    __syncthreads();
    if (t < 8) {
        int ws = wsum[t];
        int vv = ws;
        for (int d = 1; d < 8; d <<= 1) {
            int u = __shfl_up(vv, d, 64);
            if (t >= d) vv += u;
        }
        wsum[t] = vv - ws;
    }
    __syncthreads();
    int excl = wsum[w] + (v - s);
    cur[2 * t] = excl;
    cur[2 * t + 1] = excl + h0;
    // write bin starts (values just computed, no barrier needed)
    {
        ushort2 u2;
        u2.x = (ushort_t)excl;
        u2.y = (ushort_t)(excl + h0);
        reinterpret_cast<ushort2*>(binoff + (size_t)b * NBINS)[t] = u2;
    }
    __syncthreads();
    for (int i = t; i < cnt; i += 512) {
        int2 pk = gb[i];
        unsigned k = (unsigned)pk.x;
        int key = (int)(((k >> 21) & 0xF) << 6) | (int)(k >> 26);
        int p = atomicAdd(&cur[key], 1);
        outb[p] = pk;
    }
    __syncthreads();
    for (int i = t; i < cnt; i += 512) gb[i] = outb[i];
}

// ---------------- SpMM: band-phased, contiguous group ranges ----------------
// Wave owns RPW=16 rows; group g owns rows R..R+3 (R = (r0&63)+4g) with their
// 128-dim accumulators in registers. Band loop outer (R5-confirmed: FETCH
// 370->221 MB). Band-major sort makes the group's per-band edges ONE
// contiguous ~10-edge range: per band = 2 shfls (preloaded boundaries) + one
// 16-lane coalesced batch load + static 4-edge tiles. Per-edge target row
// (pk.x>>26 - R, in 0..3) selects the accumulator via 4-way PREDICATED fma
// (all acc indices compile-time -- rule #20); 4x fma replication is free at
// VALUBusy 23%. Tail edges clamp to the last valid edge (L1-hot line, val=0)
// -- bounded waste, no extra FETCH (the R6 lesson). Group-uniform loop
// bounds => shfl sources always within the active 16-lane group.
// MODE 0: emb_out = A*xh;   acc_h = xh + A*xh        (layer 1)
// MODE 1: emb_out = A*e1;   acc_h += A*e1            (layer 2, emb_out==xh reused)
// MODE 2: out = (acc_h + A*e2) * 0.25  (fp32 final)  (layer 3)
template <int MODE>
__global__ __launch_bounds__(256, 7) void spmm_kernel(
    const half_t* __restrict__ emb_in, const ushort_t* __restrict__ binoff,
    const int2* __restrict__ staged, int N,
    half_t* __restrict__ emb_out, half_t* __restrict__ acc_h,
    float* __restrict__ out) {
    const int wid = (blockIdx.x * blockDim.x + threadIdx.x) >> 6;
    const int lane = threadIdx.x & 63;
    const int r0 = wid * RPW;
    if (r0 >= N) return;
    const int bucket = r0 >> 6;
    const int g = lane >> 4;                          // group 0..3
    const int l16 = lane & 15;
    const int gbase = g << 4;                         // first lane of this group
    const unsigned q16 = (unsigned)l16 << 4;          // byte offset of this lane's 8 dims
    const int R = (r0 & 63) + (g << 2);               // group's first row-local
    const int2* eb = staged + (size_t)bucket * CAP;
    const char* tbl = reinterpret_cast<const char*>(emb_in);
    const ushort_t* bo = binoff + (size_t)bucket * NBINS;

    // lane l16 holds band-min(l16,12) boundaries for this group (shfl'd per band)
    const int lb = min(l16, NBANDS - 1);
    const int vS = (int)bo[lb * 64 + R];
    const int vE = (int)bo[lb * 64 + R + 4];

    half2_t acc[4][4];  // [row-in-group][dim-quad] -- only ever statically indexed
#pragma unroll
    for (int u = 0; u < 4; ++u)
#pragma unroll
        for (int s = 0; s < 4; ++s) acc[u][s] = (half2_t)0;

    for (int b = 0; b < NBANDS; ++b) {
        const int S = __shfl(vS, gbase + b, 64);  // group-uniform
        const int E = __shfl(vE, gbase + b, 64);
        for (int j0 = S; j0 < E; j0 += 16) {      // group-uniform trip count
            const int lenm1 = E - 1 - j0;         // >= 0 inside loop
            const int2 myE = eb[j0 + min(l16, lenm1)];
#pragma unroll
            for (int jj = 0; jj < 16; jj += 4) {
                int ex[4], ey[4], rr[4];
#pragma unroll
                for (int c = 0; c < 4; ++c) {
                    const int idx = jj + c;
                    const int sl = gbase + min(idx, lenm1);
                    ex[c] = __shfl(myE.x, sl, 64);
                    const int tv = __shfl(myE.y, sl, 64);
                    ey[c] = (idx <= lenm1) ? tv : 0;
                    rr[c] = (int)((unsigned)ex[c] >> 26) - R;
                }
                int4 t4[4];
#pragma unroll
                for (int c = 0; c < 4; ++c) {
                    t4[c] = *reinterpret_cast<const int4*>(
                        tbl + (((unsigned)ex[c] & 0x03FFFF00u) + q16));
                }
#pragma unroll
                for (int c = 0; c < 4; ++c) {
                    const half2_t vv = h2(ey[c]);
                    const int rc = rr[c];
#pragma unroll
                    for (int q = 0; q < 4; ++q) {
                        const half2_t vq = (rc == q) ? vv : (half2_t)0;
                        acc[q][0] = h2(t4[c].x) * vq + acc[q][0];
                        acc[q][1] = h2(t4[c].y) * vq + acc[q][1];
                        acc[q][2] = h2(t4[c].z) * vq + acc[q][2];
                        acc[q][3] = h2(t4[c].w) * vq + acc[q][3];
                    }
                }
            }
        }
    }

    // each group writes its own 4 rows; no cross-group reduction needed
#pragma unroll
    for (int rr = 0; rr < 4; ++rr) {
        const int r = r0 + (g << 2) + rr;
        const size_t o = (size_t)r * DIMS + ((size_t)l16 << 3);  // 8 halves / lane
        const half2_t a0 = acc[rr][0], a1 = acc[rr][1];
        const half2_t a2 = acc[rr][2], a3 = acc[rr][3];
        if (MODE == 0 || MODE == 1) {
            *reinterpret_cast<int4*>(&emb_out[o]) = make_int4(ih(a0), ih(a1), ih(a2), ih(a3));
        }
        if (MODE == 0) {
            int4 xv = *reinterpret_cast<const int4*>(&emb_in[o]);
            *reinterpret_cast<int4*>(&acc_h[o]) = make_int4(
                ih(h2(xv.x) + a0), ih(h2(xv.y) + a1), ih(h2(xv.z) + a2), ih(h2(xv.w) + a3));
        } else if (MODE == 1) {
            int4 cv = *reinterpret_cast<const int4*>(&acc_h[o]);
            *reinterpret_cast<int4*>(&acc_h[o]) = make_int4(
                ih(h2(cv.x) + a0), ih(h2(cv.y) + a1), ih(h2(cv.z) + a2), ih(h2(cv.w) + a3));
        } else {
            int4 cv = *reinterpret_cast<const int4*>(&acc_h[o]);
            half2_t c0 = h2(cv.x), c1 = h2(cv.y), c2 = h2(cv.z), c3 = h2(cv.w);
            float4 f0 = make_float4(((float)c0.x + (float)a0.x) * 0.25f,
                                    ((float)c0.y + (float)a0.y) * 0.25f,
                                    ((float)c1.x + (float)a1.x) * 0.25f,
                                    ((float)c1.y + (float)a1.y) * 0.25f);
            float4 f1 = make_float4(((float)c2.x + (float)a2.x) * 0.25f,
                                    ((float)c2.y + (float)a2.y) * 0.25f,
                                    ((float)c3.x + (float)a3.x) * 0.25f,
                                    ((float)c3.y + (float)a3.y) * 0.25f);
            float4* po = reinterpret_cast<float4*>(&out[o]);
            po[0] = f0;
            po[1] = f1;
        }
    }
}

// ---------------- launch ----------------

extern "C" void kernel_launch(void* const* d_in, const int* in_sizes, int n_in,
                              void* d_out, int out_size, void* d_ws, size_t ws_size,
                              hipStream_t stream) {
    const float* x = (const float*)d_in[0];
    const int* erow = (const int*)d_in[1];
    const int* ecol = (const int*)d_in[2];
    const float* eval = (const float*)d_in[3];
    const int N = in_sizes[0] / DIMS;  // 100000
    const int E = in_sizes[1];         // 3200000
    float* out = (float*)d_out;
    const int nbk = (N + RPB - 1) / RPB;  // 1563

    char* ws = (char*)d_ws;
    size_t off = 0;
    auto carve = [&](size_t bytes) {
        void* p = ws + off;
        off = (off + bytes + 255) & ~(size_t)255;
        return p;
    };
    half_t* xh = (half_t*)carve((size_t)N * DIMS * sizeof(half_t));  // also layer-2 output
    half_t* embB1 = (half_t*)carve((size_t)N * DIMS * sizeof(half_t));
    half_t* acc_h = (half_t*)carve((size_t)N * DIMS * sizeof(half_t));
    int2* staged = (int2*)carve((size_t)nbk * CAP * sizeof(int2));
    int* fill = (int*)carve((size_t)nbk * sizeof(int));
    ushort_t* binoff = (ushort_t*)carve((size_t)nbk * NBINS * sizeof(ushort_t));
    (void)ws_size;

    hipMemsetAsync(fill, 0, (size_t)nbk * sizeof(int), stream);
    const int n2 = N * DIMS / 2;
    cvt_kernel<<<(n2 + 255) / 256, 256, 0, stream>>>(x, xh, n2);
    binA_kernel<<<(E + 8191) / 8192, 512, 0, stream>>>(erow, ecol, eval, E, nbk, fill, staged);
    sort_bucket<<<nbk, 512, 0, stream>>>(fill, staged, binoff);

    const int waves = (N + RPW - 1) / RPW;        // 6250
    const int spmm_blocks = (waves + 3) / 4;      // 1563 blocks, fully co-resident
    spmm_kernel<0><<<spmm_blocks, 256, 0, stream>>>(xh, binoff, staged, N, embB1, acc_h, out);
    spmm_kernel<1><<<spmm_blocks, 256, 0, stream>>>(embB1, binoff, staged, N, xh, acc_h, out);
    spmm_kernel<2><<<spmm_blocks, 256, 0, stream>>>(xh, binoff, staged, N, embB1, acc_h, out);
}

// Round 8
// 540.831 us; speedup vs baseline: 1.2498x; 1.0885x over previous
//
#include <hip/hip_runtime.h>

#define DIMS 128
#define RPB 64           // rows per bucket
#define CAP 3072         // edge capacity per bucket (avg 2047, ~23 sigma margin)
#define NBK_MAX 1600
#define NBINS 1024       // 64 rows x 16 column bands (col band = col>>13 in [0,12])

typedef _Float16 half_t;
typedef _Float16 half2_t __attribute__((ext_vector_type(2)));

static __device__ __forceinline__ unsigned halfbits(float v) {
    half_t h = (half_t)v;
    unsigned short us;
    __builtin_memcpy(&us, &h, 2);
    return (unsigned)us;
}
static __device__ __forceinline__ half2_t h2(int b) { return __builtin_bit_cast(half2_t, b); }
static __device__ __forceinline__ int ih(half2_t h) { return __builtin_bit_cast(int, h); }

// fp32 -> fp16 convert (x -> xh), 2 elems/thread
__global__ void cvt_kernel(const float* __restrict__ src, half_t* __restrict__ dst, int n2) {
    int i = blockIdx.x * blockDim.x + threadIdx.x;
    if (i >= n2) return;
    float2 v = reinterpret_cast<const float2*>(src)[i];
    half2_t h;
    h.x = (half_t)v.x;
    h.y = (half_t)v.y;
    reinterpret_cast<half2_t*>(&dst[0])[i] = h;
}

// Binning pass: append (rl<<26 | col<<8, half2{v,v}) to bucket row>>6.
// col<<8 IS the byte offset into the fp16 table (col*128*2).
__global__ __launch_bounds__(512) void binA_kernel(
    const int* __restrict__ row, const int* __restrict__ col,
    const float* __restrict__ val, int E, int nbk,
    int* __restrict__ fill, int2* __restrict__ staged) {
    __shared__ int cnt[NBK_MAX];
    __shared__ int base[NBK_MAX];
    const int t = threadIdx.x;
    const int tile0 = blockIdx.x * 8192;
    for (int j = t; j < nbk; j += 512) cnt[j] = 0;
    __syncthreads();
    for (int k = 0; k < 4; ++k) {
        int e = tile0 + (k * 512 + t) * 4;
        if (e + 3 < E) {
            int4 r4 = *reinterpret_cast<const int4*>(&row[e]);
            atomicAdd(&cnt[r4.x >> 6], 1);
            atomicAdd(&cnt[r4.y >> 6], 1);
            atomicAdd(&cnt[r4.z >> 6], 1);
            atomicAdd(&cnt[r4.w >> 6], 1);
        } else {
            for (int j = e; j < E; ++j) atomicAdd(&cnt[row[j] >> 6], 1);
        }
    }
    __syncthreads();
    for (int j = t; j < nbk; j += 512) {
        int c = cnt[j];
        base[j] = c ? atomicAdd(&fill[j], c) : 0;
        cnt[j] = 0;
    }
    __syncthreads();
    for (int k = 0; k < 4; ++k) {
        int e = tile0 + (k * 512 + t) * 4;
        int n = (e + 3 < E) ? 4 : max(0, E - e);
        if (n == 4) {
            int4 r4 = *reinterpret_cast<const int4*>(&row[e]);
            int4 c4 = *reinterpret_cast<const int4*>(&col[e]);
            float4 v4 = *reinterpret_cast<const float4*>(&val[e]);
            int rr[4] = {r4.x, r4.y, r4.z, r4.w};
            int cc[4] = {c4.x, c4.y, c4.z, c4.w};
            float vv[4] = {v4.x, v4.y, v4.z, v4.w};
#pragma unroll
            for (int j = 0; j < 4; ++j) {
                int b = rr[j] >> 6;
                int p = base[b] + atomicAdd(&cnt[b], 1);
                if (p < CAP) {
                    unsigned hb = halfbits(vv[j]);
                    int2 pk;
                    pk.x = (int)(((unsigned)(rr[j] & 63) << 26) | ((unsigned)cc[j] << 8));
                    pk.y = (int)((hb << 16) | hb);
                    staged[(size_t)b * CAP + p] = pk;
                }
            }
        } else {
            for (int j = e; j < e + n; ++j) {
                int r = row[j];
                int b = r >> 6;
                int p = base[b] + atomicAdd(&cnt[b], 1);
                if (p < CAP) {
                    unsigned hb = halfbits(val[j]);
                    int2 pk;
                    pk.x = (int)(((unsigned)(r & 63) << 26) | ((unsigned)col[j] << 8));
                    pk.y = (int)((hb << 16) | hb);
                    staged[(size_t)b * CAP + p] = pk;
                }
            }
        }
    }
}

// In-LDS counting sort of one bucket by (row_local, col band): key =
// (rl<<4)|band. Emits per-row (start<<16 | end) relative to bucket base.
// No input-side LDS buffer: the bucket's 16 KB stays L2-hot between the
// histogram and scatter passes, so LDS = outb+cur = 28 KB -> 4 blocks/CU.
__global__ __launch_bounds__(512) void sort_bucket(
    const int* __restrict__ fill, int2* __restrict__ staged,
    int* __restrict__ rowinfo, int N) {
    __shared__ int2 outb[CAP];   // 24 KB
    __shared__ int cur[NBINS];   // 4 KB
    __shared__ int wsum[8];
    const int b = blockIdx.x;
    const int t = threadIdx.x;
    const int w = t >> 6, lane = t & 63;
    const int cnt = min(fill[b], CAP);
    int2* gb = staged + (size_t)b * CAP;

    cur[2 * t] = 0;
    cur[2 * t + 1] = 0;
    __syncthreads();
    for (int i = t; i < cnt; i += 512) {
        unsigned k = (unsigned)gb[i].x;
        int key = (int)((k >> 26) << 4) | (int)((k >> 21) & 0xF);
        atomicAdd(&cur[key], 1);
    }
    __syncthreads();
    int h0 = cur[2 * t], h1 = cur[2 * t + 1];
    int s = h0 + h1;
    int v = s;
    for (int d = 1; d < 64; d <<= 1) {
        int u = __shfl_up(v, d, 64);
        if (lane >= d) v += u;
    }
    if (lane == 63) wsum[w] = v;
    __syncthreads();
    if (t < 8) {
        int ws = wsum[t];
        int vv = ws;
        for (int d = 1; d < 8; d <<= 1) {
            int u = __shfl_up(vv, d, 64);
            if (t >= d) vv += u;
        }
        wsum[t] = vv - ws;
    }
    __syncthreads();
    int excl = wsum[w] + (v - s);
    cur[2 * t] = excl;
    cur[2 * t + 1] = excl + h0;
    __syncthreads();
    if (t < RPB) {
        int start = cur[t * 16];
        int end = (t == RPB - 1) ? cnt : cur[t * 16 + 16];
        int r = b * RPB + t;
        if (r < N) rowinfo[r] = (start << 16) | end;
    }
    __syncthreads();
    for (int i = t; i < cnt; i += 512) {
        int2 pk = gb[i];
        unsigned k = (unsigned)pk.x;
        int key = (int)((k >> 26) << 4) | (int)((k >> 21) & 0xF);
        int p = atomicAdd(&cur[key], 1);
        outb[p] = pk;
    }
    __syncthreads();
    for (int i = t; i < cnt; i += 512) gb[i] = outb[i];
}

// ---------------- SpMM: one wave per row, 16-lane edge groups ----------------
// Best-measured structure (R4: 114 us/dispatch, FETCH 370 MB, 3.8 TB/s
// combined). Confirmed memory-system-bound: issue-rate cuts null (R3);
// fetch-volume cuts all rate-negative (R5 serial segments, R6 max-padding,
// R7 predicated fma). One coalesced edge-batch load per 64 edges; 16-lane
// groups x dwordx4 gathers (8 lines in flight per instruction); tail is one
// masked statically-indexed iteration (rule #20).
// MODE 0: emb_out = A*xh;   acc_h = xh + A*xh        (layer 1)
// MODE 1: emb_out = A*e1;   acc_h += A*e1            (layer 2, emb_out==xh reused)
// MODE 2: out = (acc_h + A*e2) * 0.25  (fp32 final)  (layer 3)
template <int MODE>
__global__ __launch_bounds__(256) void spmm_kernel(
    const half_t* __restrict__ emb_in, const int* __restrict__ rowinfo,
    const int2* __restrict__ staged, int N,
    half_t* __restrict__ emb_out, half_t* __restrict__ acc_h,
    float* __restrict__ out) {
    const int r = (blockIdx.x * blockDim.x + threadIdx.x) >> 6;  // wave id = row
    const int lane = threadIdx.x & 63;
    if (r >= N) return;
    const int info = rowinfo[r];
    const int start = info >> 16;
    const int end = info & 0xFFFF;
    const int2* eb = staged + (size_t)(r >> 6) * CAP;
    const char* tbl = reinterpret_cast<const char*>(emb_in);
    const int g = lane >> 4;                          // edge group 0..3
    const unsigned q16 = (unsigned)(lane & 15) << 4;  // byte offset of this lane's 8 dims

    half2_t acc[4][4];
#pragma unroll
    for (int u = 0; u < 4; ++u)
#pragma unroll
        for (int s = 0; s < 4; ++s) acc[u][s] = (half2_t)0;

    for (int base = start; base < end; base += 64) {
        const int cnt = min(64, end - base);
        int2 myE = make_int2(0, 0);
        if (base + lane < end) myE = eb[base + lane];

        int k = 0;
        for (; k + 16 <= cnt; k += 16) {
            int ex[4], ey[4];
#pragma unroll
            for (int u = 0; u < 4; ++u) {
                ex[u] = __shfl(myE.x, k + 4 * u + g, 64);
                ey[u] = __shfl(myE.y, k + 4 * u + g, 64);
            }
            int4 tv[4];
#pragma unroll
            for (int u = 0; u < 4; ++u) {
                unsigned voff = ((unsigned)ex[u] & 0x03FFFF00u) + q16;
                tv[u] = *reinterpret_cast<const int4*>(tbl + voff);
            }
#pragma unroll
            for (int u = 0; u < 4; ++u) {
                half2_t vv = h2(ey[u]);
                acc[u][0] = h2(tv[u].x) * vv + acc[u][0];
                acc[u][1] = h2(tv[u].y) * vv + acc[u][1];
                acc[u][2] = h2(tv[u].z) * vv + acc[u][2];
                acc[u][3] = h2(tv[u].w) * vv + acc[u][3];
            }
        }
        // tail (< 16 edges): one masked iteration, statically indexed.
        // Groups past cnt read a clamped (valid) edge but with val = 0.
        if (k < cnt) {
            int ex[4], ey[4];
#pragma unroll
            for (int u = 0; u < 4; ++u) {
                const int idx = k + 4 * u + g;
                const int cl = min(idx, cnt - 1);
                ex[u] = __shfl(myE.x, cl, 64);
                int tmp = __shfl(myE.y, cl, 64);
                ey[u] = (idx < cnt) ? tmp : 0;
            }
            int4 tv[4];
#pragma unroll
            for (int u = 0; u < 4; ++u) {
                unsigned voff = ((unsigned)ex[u] & 0x03FFFF00u) + q16;
                tv[u] = *reinterpret_cast<const int4*>(tbl + voff);
            }
#pragma unroll
            for (int u = 0; u < 4; ++u) {
                half2_t vv = h2(ey[u]);
                acc[u][0] = h2(tv[u].x) * vv + acc[u][0];
                acc[u][1] = h2(tv[u].y) * vv + acc[u][1];
                acc[u][2] = h2(tv[u].z) * vv + acc[u][2];
                acc[u][3] = h2(tv[u].w) * vv + acc[u][3];
            }
        }
    }

    half2_t a0 = (acc[0][0] + acc[1][0]) + (acc[2][0] + acc[3][0]);
    half2_t a1 = (acc[0][1] + acc[1][1]) + (acc[2][1] + acc[3][1]);
    half2_t a2 = (acc[0][2] + acc[1][2]) + (acc[2][2] + acc[3][2]);
    half2_t a3 = (acc[0][3] + acc[1][3]) + (acc[2][3] + acc[3][3]);
    // combine the 4 edge groups: lanes q, q+16, q+32, q+48 hold the same dims
#pragma unroll
    for (int off = 16; off < 64; off <<= 1) {
        a0 = a0 + h2(__shfl_xor(ih(a0), off, 64));
        a1 = a1 + h2(__shfl_xor(ih(a1), off, 64));
        a2 = a2 + h2(__shfl_xor(ih(a2), off, 64));
        a3 = a3 + h2(__shfl_xor(ih(a3), off, 64));
    }

    if (lane < 16) {
        const size_t o = (size_t)r * DIMS + ((size_t)lane << 3);  // 8 halves / lane
        if (MODE == 0 || MODE == 1) {
            *reinterpret_cast<int4*>(&emb_out[o]) = make_int4(ih(a0), ih(a1), ih(a2), ih(a3));
        }
        if (MODE == 0) {
            int4 xv = *reinterpret_cast<const int4*>(&emb_in[o]);
            *reinterpret_cast<int4*>(&acc_h[o]) = make_int4(
                ih(h2(xv.x) + a0), ih(h2(xv.y) + a1), ih(h2(xv.z) + a2), ih(h2(xv.w) + a3));
        } else if (MODE == 1) {
            int4 cv = *reinterpret_cast<const int4*>(&acc_h[o]);
            *reinterpret_cast<int4*>(&acc_h[o]) = make_int4(
                ih(h2(cv.x) + a0), ih(h2(cv.y) + a1), ih(h2(cv.z) + a2), ih(h2(cv.w) + a3));
        } else {
            int4 cv = *reinterpret_cast<const int4*>(&acc_h[o]);
            half2_t c0 = h2(cv.x), c1 = h2(cv.y), c2 = h2(cv.z), c3 = h2(cv.w);
            float4 f0 = make_float4(((float)c0.x + (float)a0.x) * 0.25f,
                                    ((float)c0.y + (float)a0.y) * 0.25f,
                                    ((float)c1.x + (float)a1.x) * 0.25f,
                                    ((float)c1.y + (float)a1.y) * 0.25f);
            float4 f1 = make_float4(((float)c2.x + (float)a2.x) * 0.25f,
                                    ((float)c2.y + (float)a2.y) * 0.25f,
                                    ((float)c3.x + (float)a3.x) * 0.25f,
                                    ((float)c3.y + (float)a3.y) * 0.25f);
            float4* po = reinterpret_cast<float4*>(&out[o]);
            po[0] = f0;
            po[1] = f1;
        }
    }
}

// ---------------- launch ----------------

extern "C" void kernel_launch(void* const* d_in, const int* in_sizes, int n_in,
                              void* d_out, int out_size, void* d_ws, size_t ws_size,
                              hipStream_t stream) {
    const float* x = (const float*)d_in[0];
    const int* erow = (const int*)d_in[1];
    const int* ecol = (const int*)d_in[2];
    const float* eval = (const float*)d_in[3];
    const int N = in_sizes[0] / DIMS;  // 100000
    const int E = in_sizes[1];         // 3200000
    float* out = (float*)d_out;
    const int nbk = (N + RPB - 1) / RPB;  // 1563

    char* ws = (char*)d_ws;
    size_t off = 0;
    auto carve = [&](size_t bytes) {
        void* p = ws + off;
        off = (off + bytes + 255) & ~(size_t)255;
        return p;
    };
    half_t* xh = (half_t*)carve((size_t)N * DIMS * sizeof(half_t));  // also layer-2 output
    half_t* embB1 = (half_t*)carve((size_t)N * DIMS * sizeof(half_t));
    half_t* acc_h = (half_t*)carve((size_t)N * DIMS * sizeof(half_t));
    int2* staged = (int2*)carve((size_t)nbk * CAP * sizeof(int2));
    int* fill = (int*)carve((size_t)nbk * sizeof(int));
    int* rowinfo = (int*)carve((size_t)N * sizeof(int));
    (void)ws_size;

    hipMemsetAsync(fill, 0, (size_t)nbk * sizeof(int), stream);
    const int n2 = N * DIMS / 2;
    cvt_kernel<<<(n2 + 255) / 256, 256, 0, stream>>>(x, xh, n2);
    binA_kernel<<<(E + 8191) / 8192, 512, 0, stream>>>(erow, ecol, eval, E, nbk, fill, staged);
    sort_bucket<<<nbk, 512, 0, stream>>>(fill, staged, rowinfo, N);

    const int spmm_blocks = (N + 3) / 4;  // 4 waves (rows) per 256-thread block
    spmm_kernel<0><<<spmm_blocks, 256, 0, stream>>>(xh, rowinfo, staged, N, embB1, acc_h, out);
    spmm_kernel<1><<<spmm_blocks, 256, 0, stream>>>(embB1, rowinfo, staged, N, xh, acc_h, out);
    spmm_kernel<2><<<spmm_blocks, 256, 0, stream>>>(xh, rowinfo, staged, N, embB1, acc_h, out);
}